// Round 3
// baseline (9757.409 us; speedup 1.0000x reference)
//
#include <hip/hip_runtime.h>
#include <hip/hip_bf16.h>
#include <math.h>

#define T_ 32
#define B_ 64
#define S_ 64
#define D_ 1024

typedef __attribute__((ext_vector_type(8))) short short8;
typedef __attribute__((ext_vector_type(4))) float floatx4;

__device__ inline floatx4 mfma16(short8 a, short8 b, floatx4 c){
  return __builtin_amdgcn_mfma_f32_16x16x32_bf16(a, b, c, 0, 0, 0);
}
__device__ inline float sigm(float x){ return 1.0f/(1.0f+__expf(-x)); }

// ---- fp32 <-> bf16-bits helpers (inputs are float32; MFMA wants bf16) ----
__device__ inline short bfbits(float v){
  unsigned u = __builtin_bit_cast(unsigned, v);
  unsigned r = (u + 0x7FFFu + ((u >> 16) & 1u)) >> 16;   // RNE
  return (short)r;
}
__device__ inline float bitsf(short s){
  unsigned u = ((unsigned)(unsigned short)s) << 16;
  return __builtin_bit_cast(float, u);
}
struct bfp { short8 hi, lo; };
__device__ inline bfp cvt8(const float* p){
  bfp r;
#pragma unroll
  for (int j = 0; j < 8; ++j){
    float v = p[j];
    short h = bfbits(v);
    r.hi[j] = h;
    r.lo[j] = bfbits(v - bitsf(h));
  }
  return r;
}
__device__ inline floatx4 mfma3(const bfp& a, const bfp& b, floatx4 c){
  c = mfma16(a.lo, b.hi, c);
  c = mfma16(a.hi, b.lo, c);
  c = mfma16(a.hi, b.hi, c);
  return c;
}

// ---------------- embedding gather (padding_idx=0 -> zeros) ----------------
__global__ __launch_bounds__(256) void embed_kernel(const int* __restrict__ tok,
                                                    const float* __restrict__ emb,
                                                    float* __restrict__ x0){
  int i = blockIdx.x*256 + threadIdx.x;   // float4 groups; total T*B*D/4 = 524288
  int d4 = i & 255;                        // 256 groups per row of D=1024
  int tb = i >> 8;
  int idx = tok[tb];
  float4 v;
  if (idx == 0) { v.x = v.y = v.z = v.w = 0.f; }
  else          { v = ((const float4*)(emb + (size_t)idx*D_))[d4]; }
  ((float4*)(x0 + (size_t)tb*D_))[d4] = v;
}

// ---- GEMM: C(M,N) = act( A1(M,K1)@B1(N,K1)^T [+ A2(M,K2)@B2(N,K2)^T] ), fp32 ----
// block = 4 waves; wave w computes rows [by*64+w*16,+16) x cols [bx*64,+64)
__global__ __launch_bounds__(256) void gemm_f32(
    const float* __restrict__ A1, int lda1, const float* __restrict__ B1, int ldb1, int K1,
    const float* __restrict__ A2, int lda2, const float* __restrict__ B2, int ldb2, int K2,
    float* __restrict__ C, int ldc, int act)
{
  int wave = threadIdx.x >> 6;
  int lane = threadIdx.x & 63;
  int lr = lane & 15;
  int lk = (lane >> 4) * 8;
  int m0 = blockIdx.y*64 + wave*16;
  int n0 = blockIdx.x*64;
  floatx4 acc[4] = {};
  {
    const float* a = A1 + (size_t)(m0 + lr)*lda1 + lk;
    for (int k0 = 0; k0 < K1; k0 += 32) {
      bfp av = cvt8(a + k0);
#pragma unroll
      for (int nt = 0; nt < 4; ++nt) {
        bfp bv = cvt8(B1 + (size_t)(n0 + nt*16 + lr)*ldb1 + k0 + lk);
        acc[nt] = mfma3(av, bv, acc[nt]);
      }
    }
  }
  if (A2) {
    const float* a = A2 + (size_t)(m0 + lr)*lda2 + lk;
    for (int k0 = 0; k0 < K2; k0 += 32) {
      bfp av = cvt8(a + k0);
#pragma unroll
      for (int nt = 0; nt < 4; ++nt) {
        bfp bv = cvt8(B2 + (size_t)(n0 + nt*16 + lr)*ldb2 + k0 + lk);
        acc[nt] = mfma3(av, bv, acc[nt]);
      }
    }
  }
  int rb = (lane >> 4) * 4;
#pragma unroll
  for (int nt = 0; nt < 4; ++nt) {
    int col = n0 + nt*16 + lr;
#pragma unroll
    for (int r = 0; r < 4; ++r) {
      float v = acc[nt][r];
      if (act) v = tanhf(v);
      C[(size_t)(m0 + rb + r)*ldc + col] = v;
    }
  }
}

// ---------------- LSTM state init ----------------
__global__ __launch_bounds__(256) void init_state(const float* __restrict__ h0l,
                                                  const float* __restrict__ c0l,
                                                  float* __restrict__ h, float* __restrict__ c){
  int i = blockIdx.x*256 + threadIdx.x;  // B*D
  h[i] = h0l[i];
  c[i] = c0l[i];
}

// ---- one fused LSTM timestep: gates = x_t@wih^T + h@whh^T + b; update c,h ----
// grid = 64 blocks (d-tile of 16), 256 threads = 4 waves (one per gate: i,f,g,o)
__global__ __launch_bounds__(256) void lstm_step(
    const float* __restrict__ x, int t,
    const float* __restrict__ wih, const float* __restrict__ whh,
    const float* __restrict__ bih, const float* __restrict__ bhh,
    const float* __restrict__ h_in, float* __restrict__ c,
    float* __restrict__ h_out, float* __restrict__ x_out,
    float* __restrict__ hn_out, float* __restrict__ cn_out)  // non-null only at t==T-1
{
  __shared__ float g_lds[4][64][16];
  int g = threadIdx.x >> 6;        // gate index (i,f,g,o)
  int lane = threadIdx.x & 63;
  int lr = lane & 15;
  int lk = (lane >> 4) * 8;
  int d0 = blockIdx.x * 16;
  const float* Wh = whh + (size_t)(g*D_ + d0 + lr)*D_ + lk;
  const float* Wx = wih + (size_t)(g*D_ + d0 + lr)*D_ + lk;
  floatx4 acc[4] = {};
  for (int k0 = 0; k0 < D_; k0 += 32) {
    bfp bh = cvt8(Wh + k0);
    bfp bx = cvt8(Wx + k0);
#pragma unroll
    for (int m = 0; m < 4; ++m) {
      bfp ah = cvt8(h_in + (size_t)(m*16 + lr)*D_ + k0 + lk);
      acc[m] = mfma3(ah, bh, acc[m]);
      bfp ax = cvt8(x + ((size_t)t*B_ + m*16 + lr)*D_ + k0 + lk);
      acc[m] = mfma3(ax, bx, acc[m]);
    }
  }
  float bsum = bih[g*D_ + d0 + lr] + bhh[g*D_ + d0 + lr];
  int rb = (lane >> 4) * 4;
#pragma unroll
  for (int m = 0; m < 4; ++m)
#pragma unroll
    for (int r = 0; r < 4; ++r)
      g_lds[g][m*16 + rb + r][lr] = acc[m][r] + bsum;
  __syncthreads();
#pragma unroll
  for (int j = 0; j < 4; ++j) {
    int p  = threadIdx.x + j*256;   // 1024 (b,dc) pairs
    int b  = p >> 4;
    int dc = p & 15;
    float i_ = sigm(g_lds[0][b][dc]);
    float f_ = sigm(g_lds[1][b][dc]);
    float gg = tanhf(g_lds[2][b][dc]);
    float o_ = sigm(g_lds[3][b][dc]);
    int d = d0 + dc;
    size_t ci = (size_t)b*D_ + d;
    float cn = f_*c[ci] + i_*gg;
    c[ci] = cn;
    float h = o_*tanhf(cn);
    h_out[ci] = h;
    x_out[((size_t)t*B_ + b)*D_ + d] = h;
    if (hn_out) { hn_out[ci] = h; cn_out[ci] = cn; }
  }
}

// ---------------- attention: one block per batch b ----------------
__global__ __launch_bounds__(256) void attn_kernel(
    const float* __restrict__ q,    // (T,B,D)
    const float* __restrict__ ctx,  // (S,B,D)
    float* __restrict__ wout,       // (T,B,D) weighted
    float* __restrict__ attn_out)   // (B,S): attn at t=T-1
{
  int b = blockIdx.x;
  __shared__ float sc[32][64];
  __shared__ short at_hi[32][64];
  __shared__ short at_lo[32][64];
  int wave = threadIdx.x >> 6;
  int lane = threadIdx.x & 63;
  int lr = lane & 15;
  int lk = (lane >> 4) * 8;
  int rb = (lane >> 4) * 4;

  // phase 1: scores(32,64) = Q_b(32,1024) @ CtxB(64,1024)^T
  {
    floatx4 acc[2] = {};
    int n0 = wave * 16;
    const float* Br = ctx + ((size_t)(n0 + lr)*B_ + b)*D_ + lk;  // s = n0+lr
    const float* A0 = q   + ((size_t)(0  + lr)*B_ + b)*D_ + lk;  // t = lr
    const float* A1 = q   + ((size_t)(16 + lr)*B_ + b)*D_ + lk;
    for (int k0 = 0; k0 < D_; k0 += 32) {
      bfp bb = cvt8(Br + k0);
      bfp a0 = cvt8(A0 + k0);
      acc[0] = mfma3(a0, bb, acc[0]);
      bfp a1 = cvt8(A1 + k0);
      acc[1] = mfma3(a1, bb, acc[1]);
    }
#pragma unroll
    for (int m = 0; m < 2; ++m)
#pragma unroll
      for (int r = 0; r < 4; ++r)
        sc[m*16 + rb + r][n0 + lr] = acc[m][r];
  }
  __syncthreads();

  // softmax over s; threads 0..31 each own one t
  if (threadIdx.x < 32) {
    int t = threadIdx.x;
    float mx = -1e30f;
    for (int s = 0; s < 64; ++s) mx = fmaxf(mx, sc[t][s]);
    float sum = 0.f;
    for (int s = 0; s < 64; ++s) { float v = __expf(sc[t][s] - mx); sum += v; sc[t][s] = v; }
    float inv = 1.f / sum;
    for (int s = 0; s < 64; ++s) {
      float v = sc[t][s] * inv;
      short h = bfbits(v);
      at_hi[t][s] = h;
      at_lo[t][s] = bfbits(v - bitsf(h));
      if (t == 31) attn_out[b*64 + s] = v;
    }
  }
  __syncthreads();

  // phase 2: weighted(32,1024) = attn(32,64) @ CtxB(64,1024)
  for (int i = 0; i < 16; ++i) {
    int n0 = (wave + 4*i) * 16;
    floatx4 acc[2] = {};
#pragma unroll
    for (int kk = 0; kk < 2; ++kk) {
      bfp bb;
#pragma unroll
      for (int j = 0; j < 8; ++j) {
        int s = kk*32 + (lane >> 4)*8 + j;
        float v = ctx[((size_t)s*B_ + b)*D_ + n0 + lr];
        short h = bfbits(v);
        bb.hi[j] = h;
        bb.lo[j] = bfbits(v - bitsf(h));
      }
      bfp a0, a1;
      a0.hi = *(const short8*)&at_hi[0  + lr][kk*32 + lk];
      a0.lo = *(const short8*)&at_lo[0  + lr][kk*32 + lk];
      a1.hi = *(const short8*)&at_hi[16 + lr][kk*32 + lk];
      a1.lo = *(const short8*)&at_lo[16 + lr][kk*32 + lk];
      acc[0] = mfma3(a0, bb, acc[0]);
      acc[1] = mfma3(a1, bb, acc[1]);
    }
#pragma unroll
    for (int m = 0; m < 2; ++m)
#pragma unroll
      for (int r = 0; r < 4; ++r) {
        int t = m*16 + rb + r;
        wout[((size_t)t*B_ + b)*D_ + n0 + lr] = acc[m][r];
      }
  }
}

extern "C" void kernel_launch(void* const* d_in, const int* in_sizes, int n_in,
                              void* d_out, int out_size, void* d_ws, size_t ws_size,
                              hipStream_t stream) {
  const int*   tok   = (const int*)  d_in[0];
  const float* h0    = (const float*)d_in[1];
  const float* c0    = (const float*)d_in[2];
  const float* ctx   = (const float*)d_in[3];
  const float* emb   = (const float*)d_in[5];
  const float* wih[2] = {(const float*)d_in[6],  (const float*)d_in[10]};
  const float* whh[2] = {(const float*)d_in[7],  (const float*)d_in[11]};
  const float* bih[2] = {(const float*)d_in[8],  (const float*)d_in[12]};
  const float* bhh[2] = {(const float*)d_in[9],  (const float*)d_in[13]};
  const float* w_in  = (const float*)d_in[14];
  const float* w_out = (const float*)d_in[15];
  float* outp = (float*)d_out;

  // ---- workspace: 24.75 MB ----
  char* ws = (char*)d_ws;
#define MB(x) ((size_t)(x) << 20)
  float* x0   = (float*)(ws + MB(0));   // 8 MB (T,B,D)
  float* x1   = (float*)(ws + MB(8));   // 8 MB
  float* x2   = (float*)(ws + MB(16));  // 8 MB
  float* qb   = (float*)(ws + MB(0));   // overlays x0 (dead after layer 0 consumed)
  float* wt   = (float*)(ws + MB(8));   // overlays x1 (dead after layer 1 consumed)
  float* cbuf = (float*)(ws + MB(24));                 // 256 KB
  float* hbuf = (float*)(ws + MB(24) + 262144);        // 2 x 256 KB ping-pong
#undef MB

  const size_t BD = (size_t)B_*D_;
  const size_t OUT_HN   = (size_t)T_*B_*D_;   // 2097152
  const size_t OUT_CN   = OUT_HN + 2*BD;      // 2228224
  const size_t OUT_ATTN = OUT_CN + 2*BD;      // 2359296

  embed_kernel<<<2048, 256, 0, stream>>>(tok, emb, x0);

  for (int l = 0; l < 2; ++l) {
    const float* xin = l ? x1 : x0;
    float*       xo  = l ? x2 : x1;
    init_state<<<256, 256, 0, stream>>>(h0 + (size_t)l*BD, c0 + (size_t)l*BD,
                                        hbuf, cbuf);
    for (int t = 0; t < T_; ++t) {
      bool last = (t == T_-1);
      lstm_step<<<64, 256, 0, stream>>>(
          xin, t, wih[l], whh[l], bih[l], bhh[l],
          hbuf + (size_t)(t & 1)*BD, cbuf,
          hbuf + (size_t)((t+1) & 1)*BD, xo,
          last ? outp + OUT_HN + (size_t)l*BD : nullptr,
          last ? outp + OUT_CN + (size_t)l*BD : nullptr);
    }
  }

  // q = x2 @ w_in^T
  gemm_f32<<<dim3(16, 32), 256, 0, stream>>>(x2, D_, w_in, D_, D_,
                                             nullptr, 0, nullptr, 0, 0,
                                             qb, D_, 0);
  attn_kernel<<<64, 256, 0, stream>>>(qb, ctx, wt, outp + OUT_ATTN);
  // out = tanh( wt@w_out[:, :D]^T + x2@w_out[:, D:]^T )
  gemm_f32<<<dim3(16, 32), 256, 0, stream>>>(wt, D_, w_out, 2*D_, D_,
                                             x2, D_, w_out + D_, 2*D_, D_,
                                             outp, D_, 1);
}

// Round 4
// 3882.986 us; speedup vs baseline: 2.5129x; 2.5129x over previous
//
#include <hip/hip_runtime.h>
#include <math.h>

#define T_ 32
#define B_ 64
#define S_ 64
#define D_ 1024

typedef __attribute__((ext_vector_type(8))) short short8;
typedef __attribute__((ext_vector_type(4))) float floatx4;

__device__ inline short8 ld8s(const short* p){ return *(const short8*)p; }
__device__ inline floatx4 mfma16(short8 a, short8 b, floatx4 c){
  return __builtin_amdgcn_mfma_f32_16x16x32_bf16(a, b, c, 0, 0, 0);
}
__device__ inline float sigm(float x){ return 1.0f/(1.0f+__expf(-x)); }

// ---- fp32 <-> bf16-bits helpers ----
__device__ inline short bfbits(float v){
  unsigned u = __builtin_bit_cast(unsigned, v);
  unsigned r = (u + 0x7FFFu + ((u >> 16) & 1u)) >> 16;   // RNE
  return (short)r;
}
__device__ inline float bitsf(short s){
  unsigned u = ((unsigned)(unsigned short)s) << 16;
  return __builtin_bit_cast(float, u);
}
__device__ inline void split1(float v, short& h, short& l){
  h = bfbits(v); l = bfbits(v - bitsf(h));
}
__device__ inline void pack4(const float4& v, unsigned long long ws_unused,
                             uint2& hp, uint2& lp){
  short h0,h1,h2,h3,l0,l1,l2,l3;
  split1(v.x,h0,l0); split1(v.y,h1,l1); split1(v.z,h2,l2); split1(v.w,h3,l3);
  hp.x = (unsigned short)h0 | ((unsigned)(unsigned short)h1 << 16);
  hp.y = (unsigned short)h2 | ((unsigned)(unsigned short)h3 << 16);
  lp.x = (unsigned short)l0 | ((unsigned)(unsigned short)l1 << 16);
  lp.y = (unsigned short)l2 | ((unsigned)(unsigned short)l3 << 16);
}

// ---------------- generic fp32 -> hi/lo bf16 split ----------------
__global__ __launch_bounds__(256) void split_kernel(const float* __restrict__ src,
                                                    short* __restrict__ hi,
                                                    short* __restrict__ lo){
  int i = blockIdx.x*256 + threadIdx.x;   // one float4 per thread; grid = n/4/256
  float4 v = ((const float4*)src)[i];
  uint2 hp, lp; pack4(v, 0, hp, lp);
  ((uint2*)hi)[i] = hp;
  ((uint2*)lo)[i] = lp;
}

// ---------------- embedding gather + split (padding_idx=0 -> zeros) ----------------
__global__ __launch_bounds__(256) void embed_split(const int* __restrict__ tok,
                                                   const float* __restrict__ emb,
                                                   short* __restrict__ xh,
                                                   short* __restrict__ xl){
  int i = blockIdx.x*256 + threadIdx.x;   // T*B*D/4 = 524288 -> 2048 blocks
  int d4 = i & 255;
  int tb = i >> 8;
  int idx = tok[tb];
  float4 v;
  if (idx == 0) { v.x=v.y=v.z=v.w=0.f; }
  else          { v = ((const float4*)(emb + (size_t)idx*D_))[d4]; }
  uint2 hp, lp; pack4(v, 0, hp, lp);
  ((uint2*)xh)[i] = hp;
  ((uint2*)xl)[i] = lp;
}

// ---------------- LSTM state init: split h0, copy c0 ----------------
__global__ __launch_bounds__(256) void init_state(const float* __restrict__ h0l,
                                                  const float* __restrict__ c0l,
                                                  short* __restrict__ hh, short* __restrict__ hl,
                                                  float* __restrict__ c){
  int i = blockIdx.x*256 + threadIdx.x;   // B*D/4 = 16384 -> 64 blocks
  float4 v = ((const float4*)h0l)[i];
  uint2 hp, lp; pack4(v, 0, hp, lp);
  ((uint2*)hh)[i] = hp;
  ((uint2*)hl)[i] = lp;
  ((float4*)c)[i] = ((const float4*)c0l)[i];
}

// ---- GEMM on pre-split operands: C = act( A1@B1^T [+ A2@B2^T] [+ bias] ) ----
// A,B stored as separate hi/lo bf16(short) arrays, K-contiguous rows.
// block = 4 waves; wave w: rows [by*64+w*16,+16) x cols [bx*64,+64)
__global__ __launch_bounds__(256) void gemm_hl(
    const short* __restrict__ A1h, const short* __restrict__ A1l, int lda1,
    const short* __restrict__ B1h, const short* __restrict__ B1l, int ldb1, int K1,
    const short* __restrict__ A2h, const short* __restrict__ A2l, int lda2,
    const short* __restrict__ B2h, const short* __restrict__ B2l, int ldb2, int K2,
    const float* __restrict__ bias0, const float* __restrict__ bias1,
    float* __restrict__ Cf, short* __restrict__ Ch, short* __restrict__ Cl,
    int ldc, int act)
{
  int wave = threadIdx.x >> 6;
  int lane = threadIdx.x & 63;
  int lr = lane & 15;
  int lk = (lane >> 4) * 8;
  int m0 = blockIdx.y*64 + wave*16;
  int n0 = blockIdx.x*64;
  floatx4 acc[4] = {};
  {
    const short* ah = A1h + (size_t)(m0 + lr)*lda1 + lk;
    const short* al = A1l + (size_t)(m0 + lr)*lda1 + lk;
    for (int k0 = 0; k0 < K1; k0 += 32) {
      short8 vh = ld8s(ah + k0);
      short8 vl = ld8s(al + k0);
#pragma unroll
      for (int nt = 0; nt < 4; ++nt) {
        size_t bo = (size_t)(n0 + nt*16 + lr)*ldb1 + k0 + lk;
        short8 bh = ld8s(B1h + bo);
        short8 bl = ld8s(B1l + bo);
        acc[nt] = mfma16(vl, bh, acc[nt]);
        acc[nt] = mfma16(vh, bl, acc[nt]);
        acc[nt] = mfma16(vh, bh, acc[nt]);
      }
    }
  }
  if (A2h) {
    const short* ah = A2h + (size_t)(m0 + lr)*lda2 + lk;
    const short* al = A2l + (size_t)(m0 + lr)*lda2 + lk;
    for (int k0 = 0; k0 < K2; k0 += 32) {
      short8 vh = ld8s(ah + k0);
      short8 vl = ld8s(al + k0);
#pragma unroll
      for (int nt = 0; nt < 4; ++nt) {
        size_t bo = (size_t)(n0 + nt*16 + lr)*ldb2 + k0 + lk;
        short8 bh = ld8s(B2h + bo);
        short8 bl = ld8s(B2l + bo);
        acc[nt] = mfma16(vl, bh, acc[nt]);
        acc[nt] = mfma16(vh, bl, acc[nt]);
        acc[nt] = mfma16(vh, bh, acc[nt]);
      }
    }
  }
  int rb = (lane >> 4) * 4;
#pragma unroll
  for (int nt = 0; nt < 4; ++nt) {
    int col = n0 + nt*16 + lr;
    float badd = bias0 ? (bias0[col] + bias1[col]) : 0.f;
#pragma unroll
    for (int r = 0; r < 4; ++r) {
      size_t idx = (size_t)(m0 + rb + r)*ldc + col;
      float v = acc[nt][r] + badd;
      if (act) v = tanhf(v);
      if (Cf) Cf[idx] = v;
      else { short h,l; split1(v,h,l); Ch[idx] = h; Cl[idx] = l; }
    }
  }
}

// ---- one LSTM timestep (recurrent part only): gates = xg + h@whh^T ----
// grid = 64 blocks (d-tile of 16), 4 waves (one per gate i,f,g,o)
__global__ __launch_bounds__(256) void lstm_step2(
    const float* __restrict__ xg, int t,
    const short* __restrict__ whh_h, const short* __restrict__ whh_l,
    const short* __restrict__ hih, const short* __restrict__ hil,
    float* __restrict__ c,
    short* __restrict__ hoh, short* __restrict__ hol,
    short* __restrict__ xoh, short* __restrict__ xol,
    float* __restrict__ hn_out, float* __restrict__ cn_out)
{
  __shared__ float g_lds[4][64][16];
  int g = threadIdx.x >> 6;
  int lane = threadIdx.x & 63;
  int lr = lane & 15;
  int lk = (lane >> 4) * 8;
  int d0 = blockIdx.x * 16;
  const short* Wh = whh_h + (size_t)(g*D_ + d0 + lr)*D_ + lk;
  const short* Wl = whh_l + (size_t)(g*D_ + d0 + lr)*D_ + lk;
  floatx4 acc[4] = {};
  for (int k0 = 0; k0 < D_; k0 += 32) {
    short8 bh = ld8s(Wh + k0);
    short8 bl = ld8s(Wl + k0);
#pragma unroll
    for (int m = 0; m < 4; ++m) {
      size_t hb = (size_t)(m*16 + lr)*D_ + k0 + lk;
      short8 ah = ld8s(hih + hb);
      short8 al = ld8s(hil + hb);
      acc[m] = mfma16(al, bh, acc[m]);
      acc[m] = mfma16(ah, bl, acc[m]);
      acc[m] = mfma16(ah, bh, acc[m]);
    }
  }
  int rb = (lane >> 4) * 4;
#pragma unroll
  for (int m = 0; m < 4; ++m)
#pragma unroll
    for (int r = 0; r < 4; ++r)
      g_lds[g][m*16 + rb + r][lr] = acc[m][r];
  __syncthreads();
#pragma unroll
  for (int j = 0; j < 4; ++j) {
    int p  = threadIdx.x + j*256;
    int b  = p >> 4;
    int dc = p & 15;
    int d  = d0 + dc;
    size_t xb = ((size_t)t*B_ + b)*(4*D_) + d;
    float i_ = sigm(g_lds[0][b][dc] + xg[xb        ]);
    float f_ = sigm(g_lds[1][b][dc] + xg[xb +   D_ ]);
    float gg = tanhf(g_lds[2][b][dc] + xg[xb + 2*D_]);
    float o_ = sigm(g_lds[3][b][dc] + xg[xb + 3*D_]);
    size_t ci = (size_t)b*D_ + d;
    float cn = f_*c[ci] + i_*gg;
    c[ci] = cn;
    float h = o_*tanhf(cn);
    short hh, hl; split1(h, hh, hl);
    hoh[ci] = hh; hol[ci] = hl;
    size_t xi = ((size_t)t*B_ + b)*D_ + d;
    xoh[xi] = hh; xol[xi] = hl;
    if (hn_out) { hn_out[ci] = h; cn_out[ci] = cn; }
  }
}

// ---------------- attention: one block per batch b ----------------
__global__ __launch_bounds__(256) void attn2(
    const short* __restrict__ qh, const short* __restrict__ ql,   // (T,B,D)
    const short* __restrict__ cxh, const short* __restrict__ cxl, // (S,B,D)
    short* __restrict__ wth, short* __restrict__ wtl,             // (T,B,D)
    float* __restrict__ attn_out)                                 // (B,S) at t=T-1
{
  int b = blockIdx.x;
  __shared__ float sc[32][64];
  __shared__ short at_hi[32][64];
  __shared__ short at_lo[32][64];
  int wave = threadIdx.x >> 6;
  int lane = threadIdx.x & 63;
  int lr = lane & 15;
  int lk = (lane >> 4) * 8;
  int rb = (lane >> 4) * 4;

  // phase 1: scores(32,64) = Q_b(32,1024) @ CtxB(64,1024)^T
  {
    floatx4 acc[2] = {};
    int n0 = wave * 16;
    size_t Bo = ((size_t)(n0 + lr)*B_ + b)*D_ + lk;
    size_t A0 = ((size_t)(0  + lr)*B_ + b)*D_ + lk;
    size_t A1 = ((size_t)(16 + lr)*B_ + b)*D_ + lk;
    for (int k0 = 0; k0 < D_; k0 += 32) {
      short8 bh = ld8s(cxh + Bo + k0);
      short8 bl = ld8s(cxl + Bo + k0);
      short8 a0h = ld8s(qh + A0 + k0), a0l = ld8s(ql + A0 + k0);
      acc[0] = mfma16(a0l, bh, acc[0]);
      acc[0] = mfma16(a0h, bl, acc[0]);
      acc[0] = mfma16(a0h, bh, acc[0]);
      short8 a1h = ld8s(qh + A1 + k0), a1l = ld8s(ql + A1 + k0);
      acc[1] = mfma16(a1l, bh, acc[1]);
      acc[1] = mfma16(a1h, bl, acc[1]);
      acc[1] = mfma16(a1h, bh, acc[1]);
    }
#pragma unroll
    for (int m = 0; m < 2; ++m)
#pragma unroll
      for (int r = 0; r < 4; ++r)
        sc[m*16 + rb + r][n0 + lr] = acc[m][r];
  }
  __syncthreads();

  // softmax over s; threads 0..31 each own one t
  if (threadIdx.x < 32) {
    int t = threadIdx.x;
    float mx = -1e30f;
    for (int s = 0; s < 64; ++s) mx = fmaxf(mx, sc[t][s]);
    float sum = 0.f;
    for (int s = 0; s < 64; ++s) { float v = __expf(sc[t][s] - mx); sum += v; sc[t][s] = v; }
    float inv = 1.f / sum;
    for (int s = 0; s < 64; ++s) {
      float v = sc[t][s] * inv;
      short h, l; split1(v, h, l);
      at_hi[t][s] = h; at_lo[t][s] = l;
      if (t == 31) attn_out[b*64 + s] = v;
    }
  }
  __syncthreads();

  // phase 2: weighted(32,1024) = attn(32,64) @ CtxB(64,1024)
  for (int i = 0; i < 16; ++i) {
    int n0 = (wave + 4*i) * 16;
    floatx4 acc[2] = {};
#pragma unroll
    for (int kk = 0; kk < 2; ++kk) {
      short8 bh, bl;
#pragma unroll
      for (int j = 0; j < 8; ++j) {
        int s = kk*32 + (lane >> 4)*8 + j;
        size_t o = ((size_t)s*B_ + b)*D_ + n0 + lr;
        bh[j] = cxh[o];
        bl[j] = cxl[o];
      }
      short8 a0h = *(const short8*)&at_hi[0  + lr][kk*32 + lk];
      short8 a0l = *(const short8*)&at_lo[0  + lr][kk*32 + lk];
      short8 a1h = *(const short8*)&at_hi[16 + lr][kk*32 + lk];
      short8 a1l = *(const short8*)&at_lo[16 + lr][kk*32 + lk];
      acc[0] = mfma16(a0l, bh, acc[0]);
      acc[0] = mfma16(a0h, bl, acc[0]);
      acc[0] = mfma16(a0h, bh, acc[0]);
      acc[1] = mfma16(a1l, bh, acc[1]);
      acc[1] = mfma16(a1h, bl, acc[1]);
      acc[1] = mfma16(a1h, bh, acc[1]);
    }
#pragma unroll
    for (int m = 0; m < 2; ++m)
#pragma unroll
      for (int r = 0; r < 4; ++r) {
        int t = m*16 + rb + r;
        size_t oi = ((size_t)t*B_ + b)*D_ + n0 + lr;
        float v = acc[m][r];
        short h, l; split1(v, h, l);
        wth[oi] = h; wtl[oi] = l;
      }
  }
}

extern "C" void kernel_launch(void* const* d_in, const int* in_sizes, int n_in,
                              void* d_out, int out_size, void* d_ws, size_t ws_size,
                              hipStream_t stream) {
  const int*   tok   = (const int*)  d_in[0];
  const float* h0    = (const float*)d_in[1];
  const float* c0    = (const float*)d_in[2];
  const float* ctx   = (const float*)d_in[3];
  const float* emb   = (const float*)d_in[5];
  const float* wih[2] = {(const float*)d_in[6],  (const float*)d_in[10]};
  const float* whh[2] = {(const float*)d_in[7],  (const float*)d_in[11]};
  const float* bih[2] = {(const float*)d_in[8],  (const float*)d_in[12]};
  const float* bhh[2] = {(const float*)d_in[9],  (const float*)d_in[13]};
  const float* w_in  = (const float*)d_in[14];
  const float* w_out = (const float*)d_in[15];
  float* outp = (float*)d_out;

  // ---- workspace layout (88.75 MB) ----
  char* ws = (char*)d_ws;
#define MB(x) ((size_t)(x) << 20)
  short* x0h = (short*)(ws + MB(0));    // 4 MB each (T*B*D shorts)
  short* x0l = (short*)(ws + MB(4));
  short* x1h = (short*)(ws + MB(8));
  short* x1l = (short*)(ws + MB(12));
  short* x2h = (short*)(ws + MB(16));
  short* x2l = (short*)(ws + MB(20));
  float* xg  = (float*)(ws + MB(24));   // 32 MB fp32 (T,B,4D)
  short* wihh = (short*)(ws + MB(56));  // 8 MB (4D*D shorts)
  short* wihl = (short*)(ws + MB(64));  // 8 MB
  short* whhh = (short*)(ws + MB(72));  // 8 MB
  short* whhl = (short*)(ws + MB(80));  // 8 MB
  // overlays (lifetimes disjoint):
  short* q_h  = x0h;                    // q hi/lo over x0 (dead after layer0 xg)
  short* q_l  = x0l;
  short* wt_h = x1h;                    // weighted hi/lo over x1 (dead after layer1 xg)
  short* wt_l = x1l;
  short* winh = (short*)(ws + MB(56));  // w_in hi/lo over wih buf (2 MB each)
  short* winl = (short*)(ws + MB(58));
  short* wouth = (short*)(ws + MB(60)); // w_out hi/lo (4 MB each)
  short* woutl = (short*)(ws + MB(64));
  short* cxh = (short*)(ws + MB(72));   // ctx hi/lo over whh buf (8 MB each)
  short* cxl = (short*)(ws + MB(80));
  float* cbuf = (float*)(ws + MB(88));              // 256 KB
  short* hbh  = (short*)(ws + MB(88) + 262144);     // 2 x 128 KB ping-pong hi
  short* hbl  = (short*)(ws + MB(88) + 524288);     // 2 x 128 KB ping-pong lo
#undef MB

  const size_t BD = (size_t)B_*D_;
  const size_t OUT_HN   = (size_t)T_*B_*D_;   // 2097152
  const size_t OUT_CN   = OUT_HN + 2*BD;
  const size_t OUT_ATTN = OUT_CN + 2*BD;

  embed_split<<<2048, 256, 0, stream>>>(tok, emb, x0h, x0l);

  for (int l = 0; l < 2; ++l) {
    const short* xinh = l ? x1h : x0h;
    const short* xinl = l ? x1l : x0l;
    short* xoh = l ? x2h : x1h;
    short* xol = l ? x2l : x1l;
    // split this layer's weights
    split_kernel<<<4096, 256, 0, stream>>>(wih[l], wihh, wihl);
    // xg = x @ wih^T + (bih+bhh)  : M=2048, N=4096, K=1024, fp32 out
    gemm_hl<<<dim3(64, 32), 256, 0, stream>>>(
        xinh, xinl, D_, wihh, wihl, D_, D_,
        nullptr, nullptr, 0, nullptr, nullptr, 0, 0,
        bih[l], bhh[l], xg, nullptr, nullptr, 4*D_, 0);
    split_kernel<<<4096, 256, 0, stream>>>(whh[l], whhh, whhl);
    init_state<<<64, 256, 0, stream>>>(h0 + (size_t)l*BD, c0 + (size_t)l*BD,
                                       hbh, hbl, cbuf);
    for (int t = 0; t < T_; ++t) {
      bool last = (t == T_-1);
      lstm_step2<<<64, 256, 0, stream>>>(
          xg, t, whhh, whhl,
          hbh + (size_t)(t & 1)*BD,     hbl + (size_t)(t & 1)*BD,     cbuf,
          hbh + (size_t)((t+1) & 1)*BD, hbl + (size_t)((t+1) & 1)*BD,
          xoh, xol,
          last ? outp + OUT_HN + (size_t)l*BD : nullptr,
          last ? outp + OUT_CN + (size_t)l*BD : nullptr);
    }
  }

  // split attention/projection weights (overlay wih/whh buffers, now dead)
  split_kernel<<<1024, 256, 0, stream>>>(w_in,  winh,  winl);
  split_kernel<<<2048, 256, 0, stream>>>(w_out, wouth, woutl);
  // q = x2 @ w_in^T -> hi/lo (over x0)
  gemm_hl<<<dim3(16, 32), 256, 0, stream>>>(
      x2h, x2l, D_, winh, winl, D_, D_,
      nullptr, nullptr, 0, nullptr, nullptr, 0, 0,
      nullptr, nullptr, nullptr, q_h, q_l, D_, 0);
  split_kernel<<<4096, 256, 0, stream>>>(ctx, cxh, cxl);
  attn2<<<64, 256, 0, stream>>>(q_h, q_l, cxh, cxl, wt_h, wt_l, outp + OUT_ATTN);
  // out = tanh( wt@w_out[:, :D]^T + x2@w_out[:, D:]^T ) -> fp32
  gemm_hl<<<dim3(16, 32), 256, 0, stream>>>(
      wt_h, wt_l, D_, wouth, woutl, 2*D_, D_,
      x2h, x2l, D_, wouth + D_, woutl + D_, 2*D_, D_,
      nullptr, nullptr, outp, nullptr, nullptr, D_, 1);
}